// Round 2
// baseline (288.260 us; speedup 1.0000x reference)
//
#include <hip/hip_runtime.h>

// Factored single-row attention (reference returns out[:, -1, :] only).
// ws layout (floats): M2p [0,65536) packed [k4][e][4]; Wvp [65536,131072)
// packed [d4][e][4]; v0 @131072; c @131328; w1 @131584; w2 @131840;
// dconst {sum(bk), bq.bk, sum(bq)} (3 doubles) @132096.
//   M2[f][d] = sum_e Wq[e][f] Wk[e][d]  (u = td*(x49@M2) + v0)
//   v0[d] = sum_e bq[e] Wk[e][d];  c[d] = sum_e Wk[e][d]
//   w1[f] = sum_e bk[e] Wq[e][f];  w2[f] = sum_e Wq[e][f]
// Score paths (identical to all passing rounds):
//   q-kept & s-kept : (xs_s.u + q.bk)/16   q-kept & s-mask: NEG*sum(q)/16
//   q-mask & s-kept : NEG*(xs_s.c + sum(bk))/16   both: 256e10/16
// Round-9: full occupancy. Round-8 measured VALUBusy 36% at 4 waves/SIMD
// (each wave issuing ~9% of cycles -> latency chains uncovered). Same 1024
// blocks (M2/Wvp still read once per block), now 512 threads = 8 waves:
//   prologue: waves 0,4 compute xs + fp64 scalars for batch w>>2
//   U phase : wave w owns (group w>>1, k-half w&1) for BOTH batches ->
//             per-wave loads halve, M2 traffic unchanged; 512-thread merge
//   attn    : wave w -> (batch w>>2, s-quarter w&3); proven online-softmax
//             body on the sub-range; exact 4-way merge via LDS
//   O phase : mirror of U with Wvp/yL; 512-thread final add+store
// Also expf -> __expf (v_exp_f32; ~1e-6 rel error on softmax weights,
// negligible vs 1e-3 absmax) to shorten the serial score->exp chain.
// __launch_bounds__(512,8) pins VGPR<=64 so 8 waves/SIMD is granted.

namespace {
constexpr int kB = 2048;
constexpr int kT = 50;
constexpr int kD = 256;
constexpr double kNeg = -100000.0;
constexpr int oM2 = 0;
constexpr int oWvp = 65536;
constexpr int oV0 = 131072;
constexpr int oC = 131328;
constexpr int oW1 = 131584;
constexpr int oW2 = 131840;
constexpr int oDbl = 132096;  // 3 doubles
}  // namespace

// ---------------- precomp: VERBATIM from rounds 5-8 (proven) --------------
__global__ __launch_bounds__(256) void precomp(
    const float* __restrict__ Wq, const float* __restrict__ bq,
    const float* __restrict__ Wk, const float* __restrict__ bk,
    const float* __restrict__ Wv, float* __restrict__ ws) {
  const int t = threadIdx.x;
  const int wave = t >> 6;
  const int lane = t & 63;
  const int blk = blockIdx.x;
  __shared__ float coefL[kD];
  __shared__ double red[3][4];

  if (blk < 256) {
    const int a = blk;
    coefL[t] = Wq[(size_t)t * kD + a];
    __syncthreads();
    const float* kcol = Wk + t;
    float pre[8];
#pragma unroll
    for (int k = 0; k < 8; ++k) pre[k] = kcol[(size_t)k * kD];
    float acc = 0.f;
    for (int j0 = 0; j0 < kD; j0 += 8) {
      float cur[8];
#pragma unroll
      for (int k = 0; k < 8; ++k) cur[k] = pre[k];
      const int nx = (j0 + 8 < kD) ? (j0 + 8) : 0;
#pragma unroll
      for (int k = 0; k < 8; ++k) pre[k] = kcol[(size_t)(nx + k) * kD];
#pragma unroll
      for (int k = 0; k < 8; ++k) acc += coefL[j0 + k] * cur[k];
    }
    ws[oM2 + (a >> 2) * 1024 + 4 * t + (a & 3)] = acc;
  } else if (blk < 258) {
    const float* W = (blk == 256) ? Wk : Wq;
    const float* coef = (blk == 256) ? bq : bk;
    coefL[t] = coef[t];
    __syncthreads();
    const float* col = W + t;
    float pre[8];
#pragma unroll
    for (int k = 0; k < 8; ++k) pre[k] = col[(size_t)k * kD];
    double a0 = 0.0, a1 = 0.0;
    for (int j0 = 0; j0 < kD; j0 += 8) {
      float cur[8];
#pragma unroll
      for (int k = 0; k < 8; ++k) cur[k] = pre[k];
      const int nx = (j0 + 8 < kD) ? (j0 + 8) : 0;
#pragma unroll
      for (int k = 0; k < 8; ++k) pre[k] = col[(size_t)(nx + k) * kD];
#pragma unroll
      for (int k = 0; k < 8; ++k) {
        const double w = (double)cur[k];
        a0 += (double)coefL[j0 + k] * w;
        a1 += w;
      }
    }
    if (blk == 256) {
      ws[oV0 + t] = (float)a0;
      ws[oC + t] = (float)a1;
    } else {
      ws[oW1 + t] = (float)a0;
      ws[oW2 + t] = (float)a1;
      double p0 = (double)bk[t];
      double p1 = (double)bq[t] * (double)bk[t];
      double p2 = (double)bq[t];
#pragma unroll
      for (int off = 32; off; off >>= 1) {
        p0 += __shfl_xor(p0, off);
        p1 += __shfl_xor(p1, off);
        p2 += __shfl_xor(p2, off);
      }
      if (lane == 0) {
        red[0][wave] = p0;
        red[1][wave] = p1;
        red[2][wave] = p2;
      }
      __syncthreads();
      if (t == 0) {
        double* dcw = (double*)(ws + oDbl);
        dcw[0] = red[0][0] + red[0][1] + red[0][2] + red[0][3];
        dcw[1] = red[1][0] + red[1][1] + red[1][2] + red[1][3];
        dcw[2] = red[2][0] + red[2][1] + red[2][2] + red[2][3];
      }
    }
  } else {
    const int d4b = (blk - 258) * 4;
    float4 in[4];
#pragma unroll
    for (int k = 0; k < 4; ++k)
      in[k] = *(const float4*)(Wv + (size_t)t * kD + 4 * (d4b + k));
    float4* Wvp = (float4*)(ws + oWvp);
#pragma unroll
    for (int k = 0; k < 4; ++k) Wvp[(size_t)(d4b + k) * kD + t] = in[k];
  }
}

// ------------- fused main: 8 cooperating waves per 2 batches --------------
__global__ __launch_bounds__(512, 8) void fused_main(
    const float* __restrict__ x, const int* __restrict__ mask,
    const float* __restrict__ td, const float* __restrict__ bv,
    const float* __restrict__ ws, float* __restrict__ out) {
  const int tid = threadIdx.x;
  const int lane = tid & 63;
  const int w = tid >> 6;
  const int b0 = blockIdx.x * 2;
  __shared__ __align__(16) float xsL[2][kD];
  __shared__ __align__(16) float uL[2][kD];
  __shared__ __align__(16) float yL[2][kD];
  // scratch union (time-separated by barriers):
  //   U-partials  scr[kh][j][*]   (kh,j in {0,1})
  //   attn ypart  scr[j][q][*]    (j in {0,1}, q in {0..3})
  //   O-partials  scr[kh][j][*]
  __shared__ __align__(16) float scr[2][4][kD];
  __shared__ double mpart[2][4];
  __shared__ float lpart[2][4];
  __shared__ double dScal[2][2];  // [j][0]=Qbk, [j][1]=Sq

  const double* dc = (const double*)(ws + oDbl);
  const float4* M2v = (const float4*)(ws + oM2);
  const float4* Wvv = (const float4*)(ws + oWvp);

  // attn role for this wave, and early (latency-hidden) small loads
  const int ja = w >> 2;  // batch this wave handles in the attn phase
  const int q = w & 3;    // s-quarter this wave handles
  const float mtdA = (lane < kT) ? td[(size_t)(b0 + ja) * kT + lane] : 0.f;
  const int mmkA = (lane < kT) ? mask[(size_t)(b0 + ja) * kT + lane] : 0;
  const float4 c4 = ((const float4*)(ws + oC))[lane];

  // ---- prologue: waves 0,4 (q==0) compute batch ja's xs + fp64 scalars ---
  if (q == 0) {
    const int j = ja;
    const int b = b0 + j;
    const float tdl = __shfl(mtdA, kT - 1);
    const float4 a1 = ((const float4*)(ws + oW1))[lane];
    const float4 a2 = ((const float4*)(ws + oW2))[lane];
    const float4 xv =
        ((const float4*)(x + ((size_t)b * kT + kT - 1) * kD))[lane];
    double s1 = (double)xv.x * a1.x + (double)xv.y * a1.y +
                (double)xv.z * a1.z + (double)xv.w * a1.w;
    double s2 = (double)xv.x * a2.x + (double)xv.y * a2.y +
                (double)xv.z * a2.z + (double)xv.w * a2.w;
#pragma unroll
    for (int off = 32; off; off >>= 1) {
      s1 += __shfl_xor(s1, off);
      s2 += __shfl_xor(s2, off);
    }
    if (lane == 0) {
      dScal[j][0] = (double)tdl * s1 + dc[1];
      dScal[j][1] = (double)tdl * s2 + dc[2];
    }
    float4 xs;
    xs.x = xv.x * tdl; xs.y = xv.y * tdl;
    xs.z = xv.z * tdl; xs.w = xv.w * tdl;
    *(float4*)(&xsL[j][4 * lane]) = xs;
  }
  __syncthreads();

  // ---- U phase: wave w owns (group w>>1, k-half w&1) for both batches ----
  {
    const int gU = w >> 1;
    const int kh = w & 1;
    const int col = 64 * gU + lane;
    const int kb = kh * 32;
    float4 A = M2v[(size_t)kb * 256 + col];
    float4 B = M2v[(size_t)(kb + 1) * 256 + col];
    float acc0 = 0.f, acc1 = 0.f;
    for (int k4 = kb; k4 < kb + 32; k4 += 2) {
      const float4 c0 = A, c1 = B;
      const int n0 = (k4 + 2 < kb + 32) ? k4 + 2 : kb;
      const int n1 = (k4 + 3 < kb + 32) ? k4 + 3 : kb + 1;
      A = M2v[(size_t)n0 * 256 + col];
      B = M2v[(size_t)n1 * 256 + col];
      const float4 x00 = *(const float4*)(&xsL[0][4 * k4]);
      const float4 x01 = *(const float4*)(&xsL[0][4 * (k4 + 1)]);
      const float4 x10 = *(const float4*)(&xsL[1][4 * k4]);
      const float4 x11 = *(const float4*)(&xsL[1][4 * (k4 + 1)]);
      acc0 += x00.x * c0.x + x00.y * c0.y + x00.z * c0.z + x00.w * c0.w +
              x01.x * c1.x + x01.y * c1.y + x01.z * c1.z + x01.w * c1.w;
      acc1 += x10.x * c0.x + x10.y * c0.y + x10.z * c0.z + x10.w * c0.w +
              x11.x * c1.x + x11.y * c1.y + x11.z * c1.z + x11.w * c1.w;
    }
    scr[kh][0][col] = acc0;
    scr[kh][1][col] = acc1;
  }
  __syncthreads();

  // ---- U merge: 512 threads, one element each ----
  {
    const int mj = tid >> 8;
    const int mcol = tid & 255;
    uL[mj][mcol] = scr[0][mj][mcol] + scr[1][mj][mcol] + ws[oV0 + mcol];
  }
  __syncthreads();

  // ---- attention: wave w -> (batch ja, s-quarter q); proven body on the
  //      sub-range [sbeg,send); overrun rows killed at -1e300 ----
  {
    const int j = ja;
    const int b = b0 + j;
    const float mtd = mtdA;
    const int mmk = mmkA;
    const int mqg = __shfl(mmk, kT - 1);
    const float4 u4 = *(const float4*)(&uL[j][4 * lane]);
    const float4 v4 = mqg ? u4 : c4;
    const double Qb = dScal[j][0];
    const double Cm = kNeg * dScal[j][1] * 0.0625;
    const double sbkd = dc[0];
    const double Cbb = 256.0 * 1.0e10 * 0.0625;
    // quarter bounds {0,13,26,38,50}: iters 4,4,3,3
    const int sbeg = (q == 0) ? 0 : (q == 1) ? 13 : (q == 2) ? 26 : 38;
    const int send = (q == 0) ? 13 : (q == 1) ? 26 : (q == 2) ? 38 : 50;

    const float4* xrow = (const float4*)(x + (size_t)b * kT * kD);
    double m = -1.0e300;
    float l = 0.f;
    float4 y = {0.f, 0.f, 0.f, 0.f};

    const int i0 = (sbeg + 0 < kT) ? sbeg + 0 : kT - 1;
    const int i1 = (sbeg + 1 < kT) ? sbeg + 1 : kT - 1;
    const int i2 = (sbeg + 2 < kT) ? sbeg + 2 : kT - 1;
    const int i3 = (sbeg + 3 < kT) ? sbeg + 3 : kT - 1;
    float4 n0 = xrow[(size_t)i0 * 64 + lane];
    float4 n1 = xrow[(size_t)i1 * 64 + lane];
    float4 n2 = xrow[(size_t)i2 * 64 + lane];
    float4 n3 = xrow[(size_t)i3 * 64 + lane];
    for (int s = sbeg; s < send; s += 4) {
      const float4 r0 = n0, r1 = n1, r2 = n2, r3 = n3;
      {
        const int p0 = (s + 4 < kT) ? s + 4 : kT - 1;
        const int p1 = (s + 5 < kT) ? s + 5 : kT - 1;
        const int p2 = (s + 6 < kT) ? s + 6 : kT - 1;
        const int p3 = (s + 7 < kT) ? s + 7 : kT - 1;
        n0 = xrow[(size_t)p0 * 64 + lane];
        n1 = xrow[(size_t)p1 * 64 + lane];
        n2 = xrow[(size_t)p2 * 64 + lane];
        n3 = xrow[(size_t)p3 * 64 + lane];
      }
      const int s1i = s + 1, s2i = s + 2, s3i = s + 3;
      const int cc0 = s;
      const int cc1 = (s1i < kT) ? s1i : kT - 1;
      const int cc2 = (s2i < kT) ? s2i : kT - 1;
      const int cc3 = (s3i < kT) ? s3i : kT - 1;
      const float tv0 = __shfl(mtd, cc0);
      const float tv1 = __shfl(mtd, cc1);
      const float tv2 = __shfl(mtd, cc2);
      const float tv3 = __shfl(mtd, cc3);
      float4 a0, aa1, a2v, a3;
      a0.x = r0.x * tv0; a0.y = r0.y * tv0; a0.z = r0.z * tv0; a0.w = r0.w * tv0;
      aa1.x = r1.x * tv1; aa1.y = r1.y * tv1; aa1.z = r1.z * tv1; aa1.w = r1.w * tv1;
      a2v.x = r2.x * tv2; a2v.y = r2.y * tv2; a2v.z = r2.z * tv2; a2v.w = r2.w * tv2;
      a3.x = r3.x * tv3; a3.y = r3.y * tv3; a3.z = r3.z * tv3; a3.w = r3.w * tv3;
      float p0 = a0.x * v4.x + a0.y * v4.y + a0.z * v4.z + a0.w * v4.w;
      float p1 = aa1.x * v4.x + aa1.y * v4.y + aa1.z * v4.z + aa1.w * v4.w;
      float p2 = a2v.x * v4.x + a2v.y * v4.y + a2v.z * v4.z + a2v.w * v4.w;
      float p3 = a3.x * v4.x + a3.y * v4.y + a3.z * v4.z + a3.w * v4.w;
#pragma unroll
      for (int off = 32; off; off >>= 1) {
        p0 += __shfl_xor(p0, off);
        p1 += __shfl_xor(p1, off);
        p2 += __shfl_xor(p2, off);
        p3 += __shfl_xor(p3, off);
      }
      const int ms0 = __shfl(mmk, cc0);
      const int ms1 = __shfl(mmk, cc1);
      const int ms2 = __shfl(mmk, cc2);
      const int ms3 = __shfl(mmk, cc3);
      double sc0, sc1, sc2, sc3;
      if (mqg) {
        sc0 = ms0 ? ((double)p0 + Qb) * 0.0625 : Cm;
        sc1 = ms1 ? ((double)p1 + Qb) * 0.0625 : Cm;
        sc2 = ms2 ? ((double)p2 + Qb) * 0.0625 : Cm;
        sc3 = ms3 ? ((double)p3 + Qb) * 0.0625 : Cm;
      } else {
        sc0 = ms0 ? kNeg * ((double)p0 + sbkd) * 0.0625 : Cbb;
        sc1 = ms1 ? kNeg * ((double)p1 + sbkd) * 0.0625 : Cbb;
        sc2 = ms2 ? kNeg * ((double)p2 + sbkd) * 0.0625 : Cbb;
        sc3 = ms3 ? kNeg * ((double)p3 + sbkd) * 0.0625 : Cbb;
      }
      if (s1i >= send) sc1 = -1.0e300;
      if (s2i >= send) sc2 = -1.0e300;
      if (s3i >= send) sc3 = -1.0e300;
      double mnew = m;
      if (sc0 > mnew) mnew = sc0;
      if (sc1 > mnew) mnew = sc1;
      if (sc2 > mnew) mnew = sc2;
      if (sc3 > mnew) mnew = sc3;
      const float al = __expf((float)(m - mnew));
      const float e0 = __expf((float)(sc0 - mnew));
      const float e1 = __expf((float)(sc1 - mnew));
      const float e2 = __expf((float)(sc2 - mnew));
      const float e3 = __expf((float)(sc3 - mnew));
      m = mnew;
      l = l * al + e0 + e1 + e2 + e3;
      y.x = y.x * al + e0 * a0.x + e1 * aa1.x + e2 * a2v.x + e3 * a3.x;
      y.y = y.y * al + e0 * a0.y + e1 * aa1.y + e2 * a2v.y + e3 * a3.y;
      y.z = y.z * al + e0 * a0.z + e1 * aa1.z + e2 * a2v.z + e3 * a3.z;
      y.w = y.w * al + e0 * a0.w + e1 * aa1.w + e2 * a2v.w + e3 * a3.w;
    }
    if (lane == 0) {
      mpart[j][q] = m;
      lpart[j][q] = l;
    }
    *(float4*)(&scr[j][q][4 * lane]) = y;
  }
  __syncthreads();

  // ---- merge the four online-softmax partials (exact) + normalize ----
  {
    const int mj = tid >> 8;
    const int mcol = tid & 255;
    double M = mpart[mj][0];
    if (mpart[mj][1] > M) M = mpart[mj][1];
    if (mpart[mj][2] > M) M = mpart[mj][2];
    if (mpart[mj][3] > M) M = mpart[mj][3];
    const float e0 = __expf((float)(mpart[mj][0] - M));
    const float e1 = __expf((float)(mpart[mj][1] - M));
    const float e2 = __expf((float)(mpart[mj][2] - M));
    const float e3 = __expf((float)(mpart[mj][3] - M));
    const float l = lpart[mj][0] * e0 + lpart[mj][1] * e1 +
                    lpart[mj][2] * e2 + lpart[mj][3] * e3;
    const float inv = 1.0f / l;
    const float yv = (scr[mj][0][mcol] * e0 + scr[mj][1][mcol] * e1 +
                      scr[mj][2][mcol] * e2 + scr[mj][3][mcol] * e3) *
                     inv;
    __syncthreads();  // all reads of scr done before O overwrites it
    yL[mj][mcol] = yv;
  }
  __syncthreads();

  // ---- O phase: wave w owns (group w>>1, k-half w&1); mirror of U ----
  {
    const int gU = w >> 1;
    const int kh = w & 1;
    const int col = 64 * gU + lane;
    const int kb = kh * 32;
    float4 A = Wvv[(size_t)kb * 256 + col];
    float4 B = Wvv[(size_t)(kb + 1) * 256 + col];
    float acc0 = 0.f, acc1 = 0.f;
    for (int k4 = kb; k4 < kb + 32; k4 += 2) {
      const float4 c0 = A, c1 = B;
      const int n0 = (k4 + 2 < kb + 32) ? k4 + 2 : kb;
      const int n1 = (k4 + 3 < kb + 32) ? k4 + 3 : kb + 1;
      A = Wvv[(size_t)n0 * 256 + col];
      B = Wvv[(size_t)n1 * 256 + col];
      const float4 y00 = *(const float4*)(&yL[0][4 * k4]);
      const float4 y01 = *(const float4*)(&yL[0][4 * (k4 + 1)]);
      const float4 y10 = *(const float4*)(&yL[1][4 * k4]);
      const float4 y11 = *(const float4*)(&yL[1][4 * (k4 + 1)]);
      acc0 += y00.x * c0.x + y00.y * c0.y + y00.z * c0.z + y00.w * c0.w +
              y01.x * c1.x + y01.y * c1.y + y01.z * c1.z + y01.w * c1.w;
      acc1 += y10.x * c0.x + y10.y * c0.y + y10.z * c0.z + y10.w * c0.w +
              y11.x * c1.x + y11.y * c1.y + y11.z * c1.z + y11.w * c1.w;
    }
    scr[kh][0][col] = acc0;
    scr[kh][1][col] = acc1;
  }
  __syncthreads();

  // ---- final: 512 threads, add halves + bias, coalesced store ----
  {
    const int mj = tid >> 8;
    const int mcol = tid & 255;
    out[(size_t)(b0 + mj) * kD + mcol] =
        scr[0][mj][mcol] + scr[1][mj][mcol] + bv[mcol];
  }
}

extern "C" void kernel_launch(void* const* d_in, const int* in_sizes, int n_in,
                              void* d_out, int out_size, void* d_ws,
                              size_t ws_size, hipStream_t stream) {
  const float* x = (const float*)d_in[0];
  const int* mask = (const int*)d_in[1];
  const float* td = (const float*)d_in[2];
  const float* Wq = (const float*)d_in[3];
  const float* bq = (const float*)d_in[4];
  const float* Wk = (const float*)d_in[5];
  const float* bk = (const float*)d_in[6];
  const float* Wv = (const float*)d_in[7];
  const float* bv = (const float*)d_in[8];
  float* ws = (float*)d_ws;  // ~530 KB used
  float* out = (float*)d_out;
  (void)in_sizes; (void)n_in; (void)out_size; (void)ws_size;

  hipLaunchKernelGGL(precomp, dim3(274), dim3(256), 0, stream, Wq, bq, Wk, bk,
                     Wv, ws);
  hipLaunchKernelGGL(fused_main, dim3(kB / 2), dim3(512), 0, stream, x, mask,
                     td, bv, (const float*)ws, out);
}

// Round 3
// 210.922 us; speedup vs baseline: 1.3667x; 1.3667x over previous
//
#include <hip/hip_runtime.h>

// Factored single-row attention (reference returns out[:, -1, :] only).
// ws layout (floats): M2p [0,65536) packed [k4][e][4]; Wvp [65536,131072)
// packed [d4][e][4]; v0 @131072; c @131328; w1 @131584; w2 @131840;
// dconst {sum(bk), bq.bk, sum(bq)} (3 doubles) @132096.
//   M2[f][d] = sum_e Wq[e][f] Wk[e][d]  (u = td*(x49@M2) + v0)
//   v0[d] = sum_e bq[e] Wk[e][d];  c[d] = sum_e Wk[e][d]
//   w1[f] = sum_e bk[e] Wq[e][f];  w2[f] = sum_e Wq[e][f]
// Score paths (identical to all passing rounds):
//   q-kept & s-kept : (xs_s.u + q.bk)/16   q-kept & s-mask: NEG*sum(q)/16
//   q-mask & s-kept : NEG*(xs_s.c + sum(bk))/16   both: 256e10/16
// Round-10: round-9's 8-wave split was structurally right but
// __launch_bounds__(512,8) capped VGPR at 64 -> allocator landed at 32 with
// ~450 B/thread scratch spills (WRITE_SIZE 2->235 MB, VALUBusy 13%).
// ONE change: launch_bounds (512,4) -> cap 128. Natural allocation is ~52-64
// (round-8 measured 52 for the same per-thread state), so no spill, and HW
// occupancy follows the ACTUAL VGPR count (24-32 waves/CU expected).
//   prologue: waves 0,4 compute xs + fp64 scalars for batch w>>2
//   U phase : wave w owns (group w>>1, k-half w&1) for BOTH batches
//   attn    : wave w -> (batch w>>2, s-quarter w&3); online-softmax merge
//   O phase : mirror of U with Wvp/yL; 512-thread final add+store

namespace {
constexpr int kB = 2048;
constexpr int kT = 50;
constexpr int kD = 256;
constexpr double kNeg = -100000.0;
constexpr int oM2 = 0;
constexpr int oWvp = 65536;
constexpr int oV0 = 131072;
constexpr int oC = 131328;
constexpr int oW1 = 131584;
constexpr int oW2 = 131840;
constexpr int oDbl = 132096;  // 3 doubles
}  // namespace

// ---------------- precomp: VERBATIM from rounds 5-9 (proven) --------------
__global__ __launch_bounds__(256) void precomp(
    const float* __restrict__ Wq, const float* __restrict__ bq,
    const float* __restrict__ Wk, const float* __restrict__ bk,
    const float* __restrict__ Wv, float* __restrict__ ws) {
  const int t = threadIdx.x;
  const int wave = t >> 6;
  const int lane = t & 63;
  const int blk = blockIdx.x;
  __shared__ float coefL[kD];
  __shared__ double red[3][4];

  if (blk < 256) {
    const int a = blk;
    coefL[t] = Wq[(size_t)t * kD + a];
    __syncthreads();
    const float* kcol = Wk + t;
    float pre[8];
#pragma unroll
    for (int k = 0; k < 8; ++k) pre[k] = kcol[(size_t)k * kD];
    float acc = 0.f;
    for (int j0 = 0; j0 < kD; j0 += 8) {
      float cur[8];
#pragma unroll
      for (int k = 0; k < 8; ++k) cur[k] = pre[k];
      const int nx = (j0 + 8 < kD) ? (j0 + 8) : 0;
#pragma unroll
      for (int k = 0; k < 8; ++k) pre[k] = kcol[(size_t)(nx + k) * kD];
#pragma unroll
      for (int k = 0; k < 8; ++k) acc += coefL[j0 + k] * cur[k];
    }
    ws[oM2 + (a >> 2) * 1024 + 4 * t + (a & 3)] = acc;
  } else if (blk < 258) {
    const float* W = (blk == 256) ? Wk : Wq;
    const float* coef = (blk == 256) ? bq : bk;
    coefL[t] = coef[t];
    __syncthreads();
    const float* col = W + t;
    float pre[8];
#pragma unroll
    for (int k = 0; k < 8; ++k) pre[k] = col[(size_t)k * kD];
    double a0 = 0.0, a1 = 0.0;
    for (int j0 = 0; j0 < kD; j0 += 8) {
      float cur[8];
#pragma unroll
      for (int k = 0; k < 8; ++k) cur[k] = pre[k];
      const int nx = (j0 + 8 < kD) ? (j0 + 8) : 0;
#pragma unroll
      for (int k = 0; k < 8; ++k) pre[k] = col[(size_t)(nx + k) * kD];
#pragma unroll
      for (int k = 0; k < 8; ++k) {
        const double w = (double)cur[k];
        a0 += (double)coefL[j0 + k] * w;
        a1 += w;
      }
    }
    if (blk == 256) {
      ws[oV0 + t] = (float)a0;
      ws[oC + t] = (float)a1;
    } else {
      ws[oW1 + t] = (float)a0;
      ws[oW2 + t] = (float)a1;
      double p0 = (double)bk[t];
      double p1 = (double)bq[t] * (double)bk[t];
      double p2 = (double)bq[t];
#pragma unroll
      for (int off = 32; off; off >>= 1) {
        p0 += __shfl_xor(p0, off);
        p1 += __shfl_xor(p1, off);
        p2 += __shfl_xor(p2, off);
      }
      if (lane == 0) {
        red[0][wave] = p0;
        red[1][wave] = p1;
        red[2][wave] = p2;
      }
      __syncthreads();
      if (t == 0) {
        double* dcw = (double*)(ws + oDbl);
        dcw[0] = red[0][0] + red[0][1] + red[0][2] + red[0][3];
        dcw[1] = red[1][0] + red[1][1] + red[1][2] + red[1][3];
        dcw[2] = red[2][0] + red[2][1] + red[2][2] + red[2][3];
      }
    }
  } else {
    const int d4b = (blk - 258) * 4;
    float4 in[4];
#pragma unroll
    for (int k = 0; k < 4; ++k)
      in[k] = *(const float4*)(Wv + (size_t)t * kD + 4 * (d4b + k));
    float4* Wvp = (float4*)(ws + oWvp);
#pragma unroll
    for (int k = 0; k < 4; ++k) Wvp[(size_t)(d4b + k) * kD + t] = in[k];
  }
}

// ------------- fused main: 8 cooperating waves per 2 batches --------------
__global__ __launch_bounds__(512, 4) void fused_main(
    const float* __restrict__ x, const int* __restrict__ mask,
    const float* __restrict__ td, const float* __restrict__ bv,
    const float* __restrict__ ws, float* __restrict__ out) {
  const int tid = threadIdx.x;
  const int lane = tid & 63;
  const int w = tid >> 6;
  const int b0 = blockIdx.x * 2;
  __shared__ __align__(16) float xsL[2][kD];
  __shared__ __align__(16) float uL[2][kD];
  __shared__ __align__(16) float yL[2][kD];
  // scratch union (time-separated by barriers):
  //   U-partials  scr[kh][j][*]   (kh,j in {0,1})
  //   attn ypart  scr[j][q][*]    (j in {0,1}, q in {0..3})
  //   O-partials  scr[kh][j][*]
  __shared__ __align__(16) float scr[2][4][kD];
  __shared__ double mpart[2][4];
  __shared__ float lpart[2][4];
  __shared__ double dScal[2][2];  // [j][0]=Qbk, [j][1]=Sq

  const double* dc = (const double*)(ws + oDbl);
  const float4* M2v = (const float4*)(ws + oM2);
  const float4* Wvv = (const float4*)(ws + oWvp);

  // attn role for this wave, and early (latency-hidden) small loads
  const int ja = w >> 2;  // batch this wave handles in the attn phase
  const int q = w & 3;    // s-quarter this wave handles
  const float mtdA = (lane < kT) ? td[(size_t)(b0 + ja) * kT + lane] : 0.f;
  const int mmkA = (lane < kT) ? mask[(size_t)(b0 + ja) * kT + lane] : 0;
  const float4 c4 = ((const float4*)(ws + oC))[lane];

  // ---- prologue: waves 0,4 (q==0) compute batch ja's xs + fp64 scalars ---
  if (q == 0) {
    const int j = ja;
    const int b = b0 + j;
    const float tdl = __shfl(mtdA, kT - 1);
    const float4 a1 = ((const float4*)(ws + oW1))[lane];
    const float4 a2 = ((const float4*)(ws + oW2))[lane];
    const float4 xv =
        ((const float4*)(x + ((size_t)b * kT + kT - 1) * kD))[lane];
    double s1 = (double)xv.x * a1.x + (double)xv.y * a1.y +
                (double)xv.z * a1.z + (double)xv.w * a1.w;
    double s2 = (double)xv.x * a2.x + (double)xv.y * a2.y +
                (double)xv.z * a2.z + (double)xv.w * a2.w;
#pragma unroll
    for (int off = 32; off; off >>= 1) {
      s1 += __shfl_xor(s1, off);
      s2 += __shfl_xor(s2, off);
    }
    if (lane == 0) {
      dScal[j][0] = (double)tdl * s1 + dc[1];
      dScal[j][1] = (double)tdl * s2 + dc[2];
    }
    float4 xs;
    xs.x = xv.x * tdl; xs.y = xv.y * tdl;
    xs.z = xv.z * tdl; xs.w = xv.w * tdl;
    *(float4*)(&xsL[j][4 * lane]) = xs;
  }
  __syncthreads();

  // ---- U phase: wave w owns (group w>>1, k-half w&1) for both batches ----
  {
    const int gU = w >> 1;
    const int kh = w & 1;
    const int col = 64 * gU + lane;
    const int kb = kh * 32;
    float4 A = M2v[(size_t)kb * 256 + col];
    float4 B = M2v[(size_t)(kb + 1) * 256 + col];
    float acc0 = 0.f, acc1 = 0.f;
    for (int k4 = kb; k4 < kb + 32; k4 += 2) {
      const float4 c0 = A, c1 = B;
      const int n0 = (k4 + 2 < kb + 32) ? k4 + 2 : kb;
      const int n1 = (k4 + 3 < kb + 32) ? k4 + 3 : kb + 1;
      A = M2v[(size_t)n0 * 256 + col];
      B = M2v[(size_t)n1 * 256 + col];
      const float4 x00 = *(const float4*)(&xsL[0][4 * k4]);
      const float4 x01 = *(const float4*)(&xsL[0][4 * (k4 + 1)]);
      const float4 x10 = *(const float4*)(&xsL[1][4 * k4]);
      const float4 x11 = *(const float4*)(&xsL[1][4 * (k4 + 1)]);
      acc0 += x00.x * c0.x + x00.y * c0.y + x00.z * c0.z + x00.w * c0.w +
              x01.x * c1.x + x01.y * c1.y + x01.z * c1.z + x01.w * c1.w;
      acc1 += x10.x * c0.x + x10.y * c0.y + x10.z * c0.z + x10.w * c0.w +
              x11.x * c1.x + x11.y * c1.y + x11.z * c1.z + x11.w * c1.w;
    }
    scr[kh][0][col] = acc0;
    scr[kh][1][col] = acc1;
  }
  __syncthreads();

  // ---- U merge: 512 threads, one element each ----
  {
    const int mj = tid >> 8;
    const int mcol = tid & 255;
    uL[mj][mcol] = scr[0][mj][mcol] + scr[1][mj][mcol] + ws[oV0 + mcol];
  }
  __syncthreads();

  // ---- attention: wave w -> (batch ja, s-quarter q); proven body on the
  //      sub-range [sbeg,send); overrun rows killed at -1e300 ----
  {
    const int j = ja;
    const int b = b0 + j;
    const float mtd = mtdA;
    const int mmk = mmkA;
    const int mqg = __shfl(mmk, kT - 1);
    const float4 u4 = *(const float4*)(&uL[j][4 * lane]);
    const float4 v4 = mqg ? u4 : c4;
    const double Qb = dScal[j][0];
    const double Cm = kNeg * dScal[j][1] * 0.0625;
    const double sbkd = dc[0];
    const double Cbb = 256.0 * 1.0e10 * 0.0625;
    // quarter bounds {0,13,26,38,50}: iters 4,4,3,3
    const int sbeg = (q == 0) ? 0 : (q == 1) ? 13 : (q == 2) ? 26 : 38;
    const int send = (q == 0) ? 13 : (q == 1) ? 26 : (q == 2) ? 38 : 50;

    const float4* xrow = (const float4*)(x + (size_t)b * kT * kD);
    double m = -1.0e300;
    float l = 0.f;
    float4 y = {0.f, 0.f, 0.f, 0.f};

    const int i0 = (sbeg + 0 < kT) ? sbeg + 0 : kT - 1;
    const int i1 = (sbeg + 1 < kT) ? sbeg + 1 : kT - 1;
    const int i2 = (sbeg + 2 < kT) ? sbeg + 2 : kT - 1;
    const int i3 = (sbeg + 3 < kT) ? sbeg + 3 : kT - 1;
    float4 n0 = xrow[(size_t)i0 * 64 + lane];
    float4 n1 = xrow[(size_t)i1 * 64 + lane];
    float4 n2 = xrow[(size_t)i2 * 64 + lane];
    float4 n3 = xrow[(size_t)i3 * 64 + lane];
    for (int s = sbeg; s < send; s += 4) {
      const float4 r0 = n0, r1 = n1, r2 = n2, r3 = n3;
      {
        const int p0 = (s + 4 < kT) ? s + 4 : kT - 1;
        const int p1 = (s + 5 < kT) ? s + 5 : kT - 1;
        const int p2 = (s + 6 < kT) ? s + 6 : kT - 1;
        const int p3 = (s + 7 < kT) ? s + 7 : kT - 1;
        n0 = xrow[(size_t)p0 * 64 + lane];
        n1 = xrow[(size_t)p1 * 64 + lane];
        n2 = xrow[(size_t)p2 * 64 + lane];
        n3 = xrow[(size_t)p3 * 64 + lane];
      }
      const int s1i = s + 1, s2i = s + 2, s3i = s + 3;
      const int cc0 = s;
      const int cc1 = (s1i < kT) ? s1i : kT - 1;
      const int cc2 = (s2i < kT) ? s2i : kT - 1;
      const int cc3 = (s3i < kT) ? s3i : kT - 1;
      const float tv0 = __shfl(mtd, cc0);
      const float tv1 = __shfl(mtd, cc1);
      const float tv2 = __shfl(mtd, cc2);
      const float tv3 = __shfl(mtd, cc3);
      float4 a0, aa1, a2v, a3;
      a0.x = r0.x * tv0; a0.y = r0.y * tv0; a0.z = r0.z * tv0; a0.w = r0.w * tv0;
      aa1.x = r1.x * tv1; aa1.y = r1.y * tv1; aa1.z = r1.z * tv1; aa1.w = r1.w * tv1;
      a2v.x = r2.x * tv2; a2v.y = r2.y * tv2; a2v.z = r2.z * tv2; a2v.w = r2.w * tv2;
      a3.x = r3.x * tv3; a3.y = r3.y * tv3; a3.z = r3.z * tv3; a3.w = r3.w * tv3;
      float p0 = a0.x * v4.x + a0.y * v4.y + a0.z * v4.z + a0.w * v4.w;
      float p1 = aa1.x * v4.x + aa1.y * v4.y + aa1.z * v4.z + aa1.w * v4.w;
      float p2 = a2v.x * v4.x + a2v.y * v4.y + a2v.z * v4.z + a2v.w * v4.w;
      float p3 = a3.x * v4.x + a3.y * v4.y + a3.z * v4.z + a3.w * v4.w;
#pragma unroll
      for (int off = 32; off; off >>= 1) {
        p0 += __shfl_xor(p0, off);
        p1 += __shfl_xor(p1, off);
        p2 += __shfl_xor(p2, off);
        p3 += __shfl_xor(p3, off);
      }
      const int ms0 = __shfl(mmk, cc0);
      const int ms1 = __shfl(mmk, cc1);
      const int ms2 = __shfl(mmk, cc2);
      const int ms3 = __shfl(mmk, cc3);
      double sc0, sc1, sc2, sc3;
      if (mqg) {
        sc0 = ms0 ? ((double)p0 + Qb) * 0.0625 : Cm;
        sc1 = ms1 ? ((double)p1 + Qb) * 0.0625 : Cm;
        sc2 = ms2 ? ((double)p2 + Qb) * 0.0625 : Cm;
        sc3 = ms3 ? ((double)p3 + Qb) * 0.0625 : Cm;
      } else {
        sc0 = ms0 ? kNeg * ((double)p0 + sbkd) * 0.0625 : Cbb;
        sc1 = ms1 ? kNeg * ((double)p1 + sbkd) * 0.0625 : Cbb;
        sc2 = ms2 ? kNeg * ((double)p2 + sbkd) * 0.0625 : Cbb;
        sc3 = ms3 ? kNeg * ((double)p3 + sbkd) * 0.0625 : Cbb;
      }
      if (s1i >= send) sc1 = -1.0e300;
      if (s2i >= send) sc2 = -1.0e300;
      if (s3i >= send) sc3 = -1.0e300;
      double mnew = m;
      if (sc0 > mnew) mnew = sc0;
      if (sc1 > mnew) mnew = sc1;
      if (sc2 > mnew) mnew = sc2;
      if (sc3 > mnew) mnew = sc3;
      const float al = __expf((float)(m - mnew));
      const float e0 = __expf((float)(sc0 - mnew));
      const float e1 = __expf((float)(sc1 - mnew));
      const float e2 = __expf((float)(sc2 - mnew));
      const float e3 = __expf((float)(sc3 - mnew));
      m = mnew;
      l = l * al + e0 + e1 + e2 + e3;
      y.x = y.x * al + e0 * a0.x + e1 * aa1.x + e2 * a2v.x + e3 * a3.x;
      y.y = y.y * al + e0 * a0.y + e1 * aa1.y + e2 * a2v.y + e3 * a3.y;
      y.z = y.z * al + e0 * a0.z + e1 * aa1.z + e2 * a2v.z + e3 * a3.z;
      y.w = y.w * al + e0 * a0.w + e1 * aa1.w + e2 * a2v.w + e3 * a3.w;
    }
    if (lane == 0) {
      mpart[j][q] = m;
      lpart[j][q] = l;
    }
    *(float4*)(&scr[j][q][4 * lane]) = y;
  }
  __syncthreads();

  // ---- merge the four online-softmax partials (exact) + normalize ----
  {
    const int mj = tid >> 8;
    const int mcol = tid & 255;
    double M = mpart[mj][0];
    if (mpart[mj][1] > M) M = mpart[mj][1];
    if (mpart[mj][2] > M) M = mpart[mj][2];
    if (mpart[mj][3] > M) M = mpart[mj][3];
    const float e0 = __expf((float)(mpart[mj][0] - M));
    const float e1 = __expf((float)(mpart[mj][1] - M));
    const float e2 = __expf((float)(mpart[mj][2] - M));
    const float e3 = __expf((float)(mpart[mj][3] - M));
    const float l = lpart[mj][0] * e0 + lpart[mj][1] * e1 +
                    lpart[mj][2] * e2 + lpart[mj][3] * e3;
    const float inv = 1.0f / l;
    const float yv = (scr[mj][0][mcol] * e0 + scr[mj][1][mcol] * e1 +
                      scr[mj][2][mcol] * e2 + scr[mj][3][mcol] * e3) *
                     inv;
    __syncthreads();  // all reads of scr done before O overwrites it
    yL[mj][mcol] = yv;
  }
  __syncthreads();

  // ---- O phase: wave w owns (group w>>1, k-half w&1); mirror of U ----
  {
    const int gU = w >> 1;
    const int kh = w & 1;
    const int col = 64 * gU + lane;
    const int kb = kh * 32;
    float4 A = Wvv[(size_t)kb * 256 + col];
    float4 B = Wvv[(size_t)(kb + 1) * 256 + col];
    float acc0 = 0.f, acc1 = 0.f;
    for (int k4 = kb; k4 < kb + 32; k4 += 2) {
      const float4 c0 = A, c1 = B;
      const int n0 = (k4 + 2 < kb + 32) ? k4 + 2 : kb;
      const int n1 = (k4 + 3 < kb + 32) ? k4 + 3 : kb + 1;
      A = Wvv[(size_t)n0 * 256 + col];
      B = Wvv[(size_t)n1 * 256 + col];
      const float4 y00 = *(const float4*)(&yL[0][4 * k4]);
      const float4 y01 = *(const float4*)(&yL[0][4 * (k4 + 1)]);
      const float4 y10 = *(const float4*)(&yL[1][4 * k4]);
      const float4 y11 = *(const float4*)(&yL[1][4 * (k4 + 1)]);
      acc0 += y00.x * c0.x + y00.y * c0.y + y00.z * c0.z + y00.w * c0.w +
              y01.x * c1.x + y01.y * c1.y + y01.z * c1.z + y01.w * c1.w;
      acc1 += y10.x * c0.x + y10.y * c0.y + y10.z * c0.z + y10.w * c0.w +
              y11.x * c1.x + y11.y * c1.y + y11.z * c1.z + y11.w * c1.w;
    }
    scr[kh][0][col] = acc0;
    scr[kh][1][col] = acc1;
  }
  __syncthreads();

  // ---- final: 512 threads, add halves + bias, coalesced store ----
  {
    const int mj = tid >> 8;
    const int mcol = tid & 255;
    out[(size_t)(b0 + mj) * kD + mcol] =
        scr[0][mj][mcol] + scr[1][mj][mcol] + bv[mcol];
  }
}

extern "C" void kernel_launch(void* const* d_in, const int* in_sizes, int n_in,
                              void* d_out, int out_size, void* d_ws,
                              size_t ws_size, hipStream_t stream) {
  const float* x = (const float*)d_in[0];
  const int* mask = (const int*)d_in[1];
  const float* td = (const float*)d_in[2];
  const float* Wq = (const float*)d_in[3];
  const float* bq = (const float*)d_in[4];
  const float* Wk = (const float*)d_in[5];
  const float* bk = (const float*)d_in[6];
  const float* Wv = (const float*)d_in[7];
  const float* bv = (const float*)d_in[8];
  float* ws = (float*)d_ws;  // ~530 KB used
  float* out = (float*)d_out;
  (void)in_sizes; (void)n_in; (void)out_size; (void)ws_size;

  hipLaunchKernelGGL(precomp, dim3(274), dim3(256), 0, stream, Wq, bq, Wk, bk,
                     Wv, ws);
  hipLaunchKernelGGL(fused_main, dim3(kB / 2), dim3(512), 0, stream, x, mask,
                     td, bv, (const float*)ws, out);
}

// Round 5
// 202.012 us; speedup vs baseline: 1.4269x; 1.0441x over previous
//
#include <hip/hip_runtime.h>

// Factored single-row attention (reference returns out[:, -1, :] only).
// ws layout (floats): M2p [0,65536) packed [k4][e][4]; Wvp [65536,131072)
// packed [d4][e][4]; v0 @131072; c @131328; w1 @131584; w2 @131840;
// dconst {sum(bk), bq.bk, sum(bq)} (3 doubles) @132096.
//   M2[f][d] = sum_e Wq[e][f] Wk[e][d]  (u = td*(x49@M2) + v0)
//   v0[d] = sum_e bq[e] Wk[e][d];  c[d] = sum_e Wk[e][d]
//   w1[f] = sum_e bk[e] Wq[e][f];  w2[f] = sum_e Wq[e][f]
// Score paths (identical to all passing rounds):
//   q-kept & s-kept : (xs_s.u + q.bk)/16   q-kept & s-mask: NEG*sum(q)/16
//   q-mask & s-kept : NEG*(xs_s.c + sum(bk))/16   both: 256e10/16
// Round-12: RESUBMIT of round-11 (container infra failed twice; kernel never
// executed; source re-audited: no divergent barriers, no OOB, no races).
// (a) __launch_bounds__(512) with NO min-waves arg -- rounds 9/10 proved the
// min-waves attribute forces spills (WRITE_SIZE 235/30 MB); the bare form
// (round-8) compiled the same body spill-free. (b) 4 batches per block
// (512 blocks x 8 waves): M2/Wvp L2 traffic halves (512->256 MB) and each
// weight element feeds 4 FMAs instead of 2 -- per-wave useful issue doubles,
// covering load latency with work instead of stalls. Weight prefetch 4-deep.
//   prologue: wave w<4 computes xs + fp64 scalars for batch w
//   U phase : wave w owns (group w&3, k-half w>>2), acc over 4 batches
//   attn    : wave w -> (batch w>>1, s-half w&1); [0,24)/[24,50);
//             proven online-softmax body; exact 2-way merge via LDS
//   O phase : mirror of U with Wvp/yL; 512-thread final add+store

namespace {
constexpr int kB = 2048;
constexpr int kT = 50;
constexpr int kD = 256;
constexpr int kBB = 4;  // batches per block
constexpr double kNeg = -100000.0;
constexpr int oM2 = 0;
constexpr int oWvp = 65536;
constexpr int oV0 = 131072;
constexpr int oC = 131328;
constexpr int oW1 = 131584;
constexpr int oW2 = 131840;
constexpr int oDbl = 132096;  // 3 doubles
}  // namespace

// ---------------- precomp: VERBATIM from rounds 5-11 (proven) -------------
__global__ __launch_bounds__(256) void precomp(
    const float* __restrict__ Wq, const float* __restrict__ bq,
    const float* __restrict__ Wk, const float* __restrict__ bk,
    const float* __restrict__ Wv, float* __restrict__ ws) {
  const int t = threadIdx.x;
  const int wave = t >> 6;
  const int lane = t & 63;
  const int blk = blockIdx.x;
  __shared__ float coefL[kD];
  __shared__ double red[3][4];

  if (blk < 256) {
    const int a = blk;
    coefL[t] = Wq[(size_t)t * kD + a];
    __syncthreads();
    const float* kcol = Wk + t;
    float pre[8];
#pragma unroll
    for (int k = 0; k < 8; ++k) pre[k] = kcol[(size_t)k * kD];
    float acc = 0.f;
    for (int j0 = 0; j0 < kD; j0 += 8) {
      float cur[8];
#pragma unroll
      for (int k = 0; k < 8; ++k) cur[k] = pre[k];
      const int nx = (j0 + 8 < kD) ? (j0 + 8) : 0;
#pragma unroll
      for (int k = 0; k < 8; ++k) pre[k] = kcol[(size_t)(nx + k) * kD];
#pragma unroll
      for (int k = 0; k < 8; ++k) acc += coefL[j0 + k] * cur[k];
    }
    ws[oM2 + (a >> 2) * 1024 + 4 * t + (a & 3)] = acc;
  } else if (blk < 258) {
    const float* W = (blk == 256) ? Wk : Wq;
    const float* coef = (blk == 256) ? bq : bk;
    coefL[t] = coef[t];
    __syncthreads();
    const float* col = W + t;
    float pre[8];
#pragma unroll
    for (int k = 0; k < 8; ++k) pre[k] = col[(size_t)k * kD];
    double a0 = 0.0, a1 = 0.0;
    for (int j0 = 0; j0 < kD; j0 += 8) {
      float cur[8];
#pragma unroll
      for (int k = 0; k < 8; ++k) cur[k] = pre[k];
      const int nx = (j0 + 8 < kD) ? (j0 + 8) : 0;
#pragma unroll
      for (int k = 0; k < 8; ++k) pre[k] = col[(size_t)(nx + k) * kD];
#pragma unroll
      for (int k = 0; k < 8; ++k) {
        const double w = (double)cur[k];
        a0 += (double)coefL[j0 + k] * w;
        a1 += w;
      }
    }
    if (blk == 256) {
      ws[oV0 + t] = (float)a0;
      ws[oC + t] = (float)a1;
    } else {
      ws[oW1 + t] = (float)a0;
      ws[oW2 + t] = (float)a1;
      double p0 = (double)bk[t];
      double p1 = (double)bq[t] * (double)bk[t];
      double p2 = (double)bq[t];
#pragma unroll
      for (int off = 32; off; off >>= 1) {
        p0 += __shfl_xor(p0, off);
        p1 += __shfl_xor(p1, off);
        p2 += __shfl_xor(p2, off);
      }
      if (lane == 0) {
        red[0][wave] = p0;
        red[1][wave] = p1;
        red[2][wave] = p2;
      }
      __syncthreads();
      if (t == 0) {
        double* dcw = (double*)(ws + oDbl);
        dcw[0] = red[0][0] + red[0][1] + red[0][2] + red[0][3];
        dcw[1] = red[1][0] + red[1][1] + red[1][2] + red[1][3];
        dcw[2] = red[2][0] + red[2][1] + red[2][2] + red[2][3];
      }
    }
  } else {
    const int d4b = (blk - 258) * 4;
    float4 in[4];
#pragma unroll
    for (int k = 0; k < 4; ++k)
      in[k] = *(const float4*)(Wv + (size_t)t * kD + 4 * (d4b + k));
    float4* Wvp = (float4*)(ws + oWvp);
#pragma unroll
    for (int k = 0; k < 4; ++k) Wvp[(size_t)(d4b + k) * kD + t] = in[k];
  }
}

// ------------- fused main: 8 cooperating waves per 4 batches --------------
__global__ __launch_bounds__(512) void fused_main(
    const float* __restrict__ x, const int* __restrict__ mask,
    const float* __restrict__ td, const float* __restrict__ bv,
    const float* __restrict__ ws, float* __restrict__ out) {
  const int tid = threadIdx.x;
  const int lane = tid & 63;
  const int w = tid >> 6;
  const int b0 = blockIdx.x * kBB;
  __shared__ __align__(16) float xsL[kBB][kD];
  __shared__ __align__(16) float uL[kBB][kD];
  __shared__ __align__(16) float yL[kBB][kD];
  // scratch union (time-separated by barriers):
  //   U-partials  scr[kh][jb][*]  (kh in {0,1}, jb in {0..3})
  //   attn ypart  scr[h][jb][*]   (h in {0,1})
  //   O-partials  scr[kh][jb][*]
  __shared__ __align__(16) float scr[2][kBB][kD];
  __shared__ double mpart[kBB][2];
  __shared__ float lpart[kBB][2];
  __shared__ double dScal[kBB][2];  // [jb][0]=Qbk, [jb][1]=Sq

  const double* dc = (const double*)(ws + oDbl);
  const float4* M2v = (const float4*)(ws + oM2);
  const float4* Wvv = (const float4*)(ws + oWvp);

  // attn role for this wave, and early (latency-hidden) small loads
  const int ja = w >> 1;  // batch this wave handles in the attn phase
  const int h = w & 1;    // s-half this wave handles
  const float mtdA = (lane < kT) ? td[(size_t)(b0 + ja) * kT + lane] : 0.f;
  const int mmkA = (lane < kT) ? mask[(size_t)(b0 + ja) * kT + lane] : 0;
  const float4 c4 = ((const float4*)(ws + oC))[lane];

  // ---- prologue: wave w<4 computes batch w's xs + fp64 scalars ----
  if (w < kBB) {
    const int j = w;
    const int b = b0 + j;
    const float tdl = td[(size_t)b * kT + kT - 1];
    const float4 a1 = ((const float4*)(ws + oW1))[lane];
    const float4 a2 = ((const float4*)(ws + oW2))[lane];
    const float4 xv =
        ((const float4*)(x + ((size_t)b * kT + kT - 1) * kD))[lane];
    double s1 = (double)xv.x * a1.x + (double)xv.y * a1.y +
                (double)xv.z * a1.z + (double)xv.w * a1.w;
    double s2 = (double)xv.x * a2.x + (double)xv.y * a2.y +
                (double)xv.z * a2.z + (double)xv.w * a2.w;
#pragma unroll
    for (int off = 32; off; off >>= 1) {
      s1 += __shfl_xor(s1, off);
      s2 += __shfl_xor(s2, off);
    }
    if (lane == 0) {
      dScal[j][0] = (double)tdl * s1 + dc[1];
      dScal[j][1] = (double)tdl * s2 + dc[2];
    }
    float4 xs;
    xs.x = xv.x * tdl; xs.y = xv.y * tdl;
    xs.z = xv.z * tdl; xs.w = xv.w * tdl;
    *(float4*)(&xsL[j][4 * lane]) = xs;
  }
  __syncthreads();

  // ---- U phase: wave w owns (group w&3, k-half w>>2), all 4 batches ----
  {
    const int gU = w & 3;
    const int kh = w >> 2;
    const int col = 64 * gU + lane;
    const int kb = kh * 32;
    float4 A = M2v[(size_t)(kb + 0) * 256 + col];
    float4 B = M2v[(size_t)(kb + 1) * 256 + col];
    float4 C = M2v[(size_t)(kb + 2) * 256 + col];
    float4 D = M2v[(size_t)(kb + 3) * 256 + col];
    float acc[kBB] = {0.f, 0.f, 0.f, 0.f};
    for (int k4 = kb; k4 < kb + 32; k4 += 2) {
      const float4 c0 = A, c1 = B;
      A = C;
      B = D;
      const int n0 = (k4 + 4 < kb + 32) ? k4 + 4 : kb;
      const int n1 = (k4 + 5 < kb + 32) ? k4 + 5 : kb;
      C = M2v[(size_t)n0 * 256 + col];
      D = M2v[(size_t)n1 * 256 + col];
#pragma unroll
      for (int jb = 0; jb < kBB; ++jb) {
        const float4 x0 = *(const float4*)(&xsL[jb][4 * k4]);
        const float4 x1 = *(const float4*)(&xsL[jb][4 * (k4 + 1)]);
        acc[jb] += x0.x * c0.x + x0.y * c0.y + x0.z * c0.z + x0.w * c0.w +
                   x1.x * c1.x + x1.y * c1.y + x1.z * c1.z + x1.w * c1.w;
      }
    }
#pragma unroll
    for (int jb = 0; jb < kBB; ++jb) scr[kh][jb][col] = acc[jb];
  }
  __syncthreads();

  // ---- U merge: 512 threads, two elements each ----
  {
#pragma unroll
    for (int rr = 0; rr < 2; ++rr) {
      const int idx = tid + rr * 512;
      const int mj = idx >> 8;
      const int mcol = idx & 255;
      uL[mj][mcol] = scr[0][mj][mcol] + scr[1][mj][mcol] + ws[oV0 + mcol];
    }
  }
  __syncthreads();

  // ---- attention: wave w -> (batch ja, s-half h); proven body on the
  //      sub-range; overrun rows killed at -1e300 ----
  {
    const int j = ja;
    const int b = b0 + j;
    const float mtd = mtdA;
    const int mmk = mmkA;
    const int mqg = __shfl(mmk, kT - 1);
    const float4 u4 = *(const float4*)(&uL[j][4 * lane]);
    const float4 v4 = mqg ? u4 : c4;
    const double Qb = dScal[j][0];
    const double Cm = kNeg * dScal[j][1] * 0.0625;
    const double sbkd = dc[0];
    const double Cbb = 256.0 * 1.0e10 * 0.0625;
    // halves: h0 [0,24) 6 iters exact; h1 [24,50) 7 iters, 50/51 killed
    const int sbeg = h ? 24 : 0;
    const int send = h ? 50 : 24;

    const float4* xrow = (const float4*)(x + (size_t)b * kT * kD);
    double m = -1.0e300;
    float l = 0.f;
    float4 y = {0.f, 0.f, 0.f, 0.f};

    float4 n0 = xrow[(size_t)(sbeg + 0) * 64 + lane];
    float4 n1 = xrow[(size_t)(sbeg + 1) * 64 + lane];
    float4 n2 = xrow[(size_t)(sbeg + 2) * 64 + lane];
    float4 n3 = xrow[(size_t)(sbeg + 3) * 64 + lane];
    for (int s = sbeg; s < send; s += 4) {
      const float4 r0 = n0, r1 = n1, r2 = n2, r3 = n3;
      {
        const int p0 = (s + 4 < kT) ? s + 4 : kT - 1;
        const int p1 = (s + 5 < kT) ? s + 5 : kT - 1;
        const int p2 = (s + 6 < kT) ? s + 6 : kT - 1;
        const int p3 = (s + 7 < kT) ? s + 7 : kT - 1;
        n0 = xrow[(size_t)p0 * 64 + lane];
        n1 = xrow[(size_t)p1 * 64 + lane];
        n2 = xrow[(size_t)p2 * 64 + lane];
        n3 = xrow[(size_t)p3 * 64 + lane];
      }
      const int s1i = s + 1, s2i = s + 2, s3i = s + 3;
      const int cc0 = s;
      const int cc1 = (s1i < kT) ? s1i : kT - 1;
      const int cc2 = (s2i < kT) ? s2i : kT - 1;
      const int cc3 = (s3i < kT) ? s3i : kT - 1;
      const float tv0 = __shfl(mtd, cc0);
      const float tv1 = __shfl(mtd, cc1);
      const float tv2 = __shfl(mtd, cc2);
      const float tv3 = __shfl(mtd, cc3);
      float4 a0, aa1, a2v, a3;
      a0.x = r0.x * tv0; a0.y = r0.y * tv0; a0.z = r0.z * tv0; a0.w = r0.w * tv0;
      aa1.x = r1.x * tv1; aa1.y = r1.y * tv1; aa1.z = r1.z * tv1; aa1.w = r1.w * tv1;
      a2v.x = r2.x * tv2; a2v.y = r2.y * tv2; a2v.z = r2.z * tv2; a2v.w = r2.w * tv2;
      a3.x = r3.x * tv3; a3.y = r3.y * tv3; a3.z = r3.z * tv3; a3.w = r3.w * tv3;
      float p0 = a0.x * v4.x + a0.y * v4.y + a0.z * v4.z + a0.w * v4.w;
      float p1 = aa1.x * v4.x + aa1.y * v4.y + aa1.z * v4.z + aa1.w * v4.w;
      float p2 = a2v.x * v4.x + a2v.y * v4.y + a2v.z * v4.z + a2v.w * v4.w;
      float p3 = a3.x * v4.x + a3.y * v4.y + a3.z * v4.z + a3.w * v4.w;
#pragma unroll
      for (int off = 32; off; off >>= 1) {
        p0 += __shfl_xor(p0, off);
        p1 += __shfl_xor(p1, off);
        p2 += __shfl_xor(p2, off);
        p3 += __shfl_xor(p3, off);
      }
      const int ms0 = __shfl(mmk, cc0);
      const int ms1 = __shfl(mmk, cc1);
      const int ms2 = __shfl(mmk, cc2);
      const int ms3 = __shfl(mmk, cc3);
      double sc0, sc1, sc2, sc3;
      if (mqg) {
        sc0 = ms0 ? ((double)p0 + Qb) * 0.0625 : Cm;
        sc1 = ms1 ? ((double)p1 + Qb) * 0.0625 : Cm;
        sc2 = ms2 ? ((double)p2 + Qb) * 0.0625 : Cm;
        sc3 = ms3 ? ((double)p3 + Qb) * 0.0625 : Cm;
      } else {
        sc0 = ms0 ? kNeg * ((double)p0 + sbkd) * 0.0625 : Cbb;
        sc1 = ms1 ? kNeg * ((double)p1 + sbkd) * 0.0625 : Cbb;
        sc2 = ms2 ? kNeg * ((double)p2 + sbkd) * 0.0625 : Cbb;
        sc3 = ms3 ? kNeg * ((double)p3 + sbkd) * 0.0625 : Cbb;
      }
      if (s1i >= send) sc1 = -1.0e300;
      if (s2i >= send) sc2 = -1.0e300;
      if (s3i >= send) sc3 = -1.0e300;
      double mnew = m;
      if (sc0 > mnew) mnew = sc0;
      if (sc1 > mnew) mnew = sc1;
      if (sc2 > mnew) mnew = sc2;
      if (sc3 > mnew) mnew = sc3;
      const float al = __expf((float)(m - mnew));
      const float e0 = __expf((float)(sc0 - mnew));
      const float e1 = __expf((float)(sc1 - mnew));
      const float e2 = __expf((float)(sc2 - mnew));
      const float e3 = __expf((float)(sc3 - mnew));
      m = mnew;
      l = l * al + e0 + e1 + e2 + e3;
      y.x = y.x * al + e0 * a0.x + e1 * aa1.x + e2 * a2v.x + e3 * a3.x;
      y.y = y.y * al + e0 * a0.y + e1 * aa1.y + e2 * a2v.y + e3 * a3.y;
      y.z = y.z * al + e0 * a0.z + e1 * aa1.z + e2 * a2v.z + e3 * a3.z;
      y.w = y.w * al + e0 * a0.w + e1 * aa1.w + e2 * a2v.w + e3 * a3.w;
    }
    if (lane == 0) {
      mpart[j][h] = m;
      lpart[j][h] = l;
    }
    *(float4*)(&scr[h][j][4 * lane]) = y;
  }
  __syncthreads();

  // ---- merge the two online-softmax partials (exact) + normalize ----
  {
    float yv[2];
    int mjA[2], mcolA[2];
#pragma unroll
    for (int rr = 0; rr < 2; ++rr) {
      const int idx = tid + rr * 512;
      const int mj = idx >> 8;
      const int mcol = idx & 255;
      const double m0 = mpart[mj][0], m1 = mpart[mj][1];
      const double M = (m0 > m1) ? m0 : m1;
      const float e0 = __expf((float)(m0 - M));
      const float e1 = __expf((float)(m1 - M));
      const float l = lpart[mj][0] * e0 + lpart[mj][1] * e1;
      yv[rr] = (scr[0][mj][mcol] * e0 + scr[1][mj][mcol] * e1) * (1.0f / l);
      mjA[rr] = mj;
      mcolA[rr] = mcol;
    }
    __syncthreads();  // all reads of scr done before yL write / O overwrite
    yL[mjA[0]][mcolA[0]] = yv[0];
    yL[mjA[1]][mcolA[1]] = yv[1];
  }
  __syncthreads();

  // ---- O phase: wave w owns (group w&3, k-half w>>2); mirror of U ----
  {
    const int gU = w & 3;
    const int kh = w >> 2;
    const int col = 64 * gU + lane;
    const int kb = kh * 32;
    float4 A = Wvv[(size_t)(kb + 0) * 256 + col];
    float4 B = Wvv[(size_t)(kb + 1) * 256 + col];
    float4 C = Wvv[(size_t)(kb + 2) * 256 + col];
    float4 D = Wvv[(size_t)(kb + 3) * 256 + col];
    float acc[kBB] = {0.f, 0.f, 0.f, 0.f};
    for (int k4 = kb; k4 < kb + 32; k4 += 2) {
      const float4 c0 = A, c1 = B;
      A = C;
      B = D;
      const int n0 = (k4 + 4 < kb + 32) ? k4 + 4 : kb;
      const int n1 = (k4 + 5 < kb + 32) ? k4 + 5 : kb;
      C = Wvv[(size_t)n0 * 256 + col];
      D = Wvv[(size_t)n1 * 256 + col];
#pragma unroll
      for (int jb = 0; jb < kBB; ++jb) {
        const float4 y0 = *(const float4*)(&yL[jb][4 * k4]);
        const float4 y1 = *(const float4*)(&yL[jb][4 * (k4 + 1)]);
        acc[jb] += y0.x * c0.x + y0.y * c0.y + y0.z * c0.z + y0.w * c0.w +
                   y1.x * c1.x + y1.y * c1.y + y1.z * c1.z + y1.w * c1.w;
      }
    }
#pragma unroll
    for (int jb = 0; jb < kBB; ++jb) scr[kh][jb][col] = acc[jb];
  }
  __syncthreads();

  // ---- final: 512 threads, add halves + bias, coalesced store ----
  {
#pragma unroll
    for (int rr = 0; rr < 2; ++rr) {
      const int idx = tid + rr * 512;
      const int mj = idx >> 8;
      const int mcol = idx & 255;
      out[(size_t)(b0 + mj) * kD + mcol] =
          scr[0][mj][mcol] + scr[1][mj][mcol] + bv[mcol];
    }
  }
}

extern "C" void kernel_launch(void* const* d_in, const int* in_sizes, int n_in,
                              void* d_out, int out_size, void* d_ws,
                              size_t ws_size, hipStream_t stream) {
  const float* x = (const float*)d_in[0];
  const int* mask = (const int*)d_in[1];
  const float* td = (const float*)d_in[2];
  const float* Wq = (const float*)d_in[3];
  const float* bq = (const float*)d_in[4];
  const float* Wk = (const float*)d_in[5];
  const float* bk = (const float*)d_in[6];
  const float* Wv = (const float*)d_in[7];
  const float* bv = (const float*)d_in[8];
  float* ws = (float*)d_ws;  // ~530 KB used
  float* out = (float*)d_out;
  (void)in_sizes; (void)n_in; (void)out_size; (void)ws_size;

  hipLaunchKernelGGL(precomp, dim3(274), dim3(256), 0, stream, Wq, bq, Wk, bk,
                     Wv, ws);
  hipLaunchKernelGGL(fused_main, dim3(kB / kBB), dim3(512), 0, stream, x, mask,
                     td, bv, (const float*)ws, out);
}